// Round 1
// baseline (3912.703 us; speedup 1.0000x reference)
//
#include <hip/hip_runtime.h>
#include <cstdint>

// MyRNN: out[b,t,:] = h_t where h_t = tanh(x[b,t,:]@W_xh + b_h + h_{t-1}@W_hh)
// B=64, S=512, D_IN=D_H=1024, all fp32 I/O; internal bf16 MFMA.
//
// Structure:
//  k_transpose_bf16 : W (fp32 [k][n]) -> WT (bf16 [n][k]) for both weights
//  k_xproj          : x @ W_xh (bf16 MFMA 128x128 tile), out xp bf16 [s][b][h]
//  k_rnn            : 64 WGs (4 batch-groups x 16 col-groups), W_hh^T slice in
//                     128 VGPRs/wave, per-batch-group 16-WG atomic barrier/step.

#define DIN 1024
#define DH  1024
#define NB  64
#define NS  512

typedef __attribute__((ext_vector_type(8))) unsigned short us8;
typedef __attribute__((ext_vector_type(8))) __bf16 bf8;
typedef __attribute__((ext_vector_type(4))) float f32x4;

__device__ __forceinline__ unsigned short f32_bf16(float f) {
  unsigned u = __float_as_uint(f);
  u = (u + 0x7fffu + ((u >> 16) & 1u)) >> 16;
  return (unsigned short)u;
}
__device__ __forceinline__ float bf16_f32(unsigned short h) {
  return __uint_as_float(((unsigned)h) << 16);
}
__device__ __forceinline__ bf8 as_bf8(us8 v) { return __builtin_bit_cast(bf8, v); }

// ---------------------------------------------------------------- transpose
// W fp32 [1024][1024] (k-major) -> WT bf16 [n][k]
__global__ __launch_bounds__(256) void k_transpose_bf16(
    const float* __restrict__ W, unsigned short* __restrict__ WT) {
  __shared__ float tile[32][33];
  const int b  = blockIdx.x;
  const int bn = (b & 31) * 32;   // n block
  const int bk = (b >> 5) * 32;   // k block
  const int tx = threadIdx.x & 31, ty = threadIdx.x >> 5;
#pragma unroll
  for (int i = 0; i < 4; ++i)
    tile[ty + i * 8][tx] = W[(size_t)(bk + ty + i * 8) * DH + bn + tx];
  __syncthreads();
#pragma unroll
  for (int i = 0; i < 4; ++i)
    WT[(size_t)(bn + ty + i * 8) * DIN + bk + tx] = f32_bf16(tile[tx][ty + i * 8]);
}

// ---------------------------------------------------------------- phase 1
// XOR slot swizzle: row stride is 64B (4 x 16B slots); swizzle slot by
// (row>>1)&3 so 16-lane frag reads land on 8 distinct banks (2-way = free).
__device__ __forceinline__ int lds_idx(int row, int slot) {  // ushort units
  return row * 32 + ((slot ^ ((row >> 1) & 3)) << 3);
}

__global__ __launch_bounds__(256) void k_xproj(
    const float* __restrict__ X,             // [B*S][DIN] fp32 (row = b*512+s)
    const unsigned short* __restrict__ WT,   // W_xh^T bf16 [n][k]
    unsigned short* __restrict__ XP) {       // bf16 [s][b][h]
  __shared__ unsigned short As[128 * 32];
  __shared__ unsigned short Bs[128 * 32];
  const int tid = threadIdx.x;
  const int m0 = (int)(blockIdx.x >> 3) * 128;
  const int n0 = (int)(blockIdx.x & 7) * 128;
  const int w = tid >> 6, lane = tid & 63;
  const int wm = (w >> 1) * 64, wn = (w & 1) * 64;
  const int l15 = lane & 15, lhi = lane >> 4;
  const int srow = tid >> 1;
  const int s0 = (tid & 1) * 2;
  f32x4 acc[4][4] = {};

  for (int k0 = 0; k0 < DIN; k0 += 32) {
    // stage A: 16 fp32 -> bf16 per thread (64B contiguous read)
    const float4* ga = reinterpret_cast<const float4*>(
        X + (size_t)(m0 + srow) * DIN + k0 + s0 * 8);
    float4 f0 = ga[0], f1 = ga[1], f2 = ga[2], f3 = ga[3];
    us8 v0, v1;
    v0[0] = f32_bf16(f0.x); v0[1] = f32_bf16(f0.y); v0[2] = f32_bf16(f0.z); v0[3] = f32_bf16(f0.w);
    v0[4] = f32_bf16(f1.x); v0[5] = f32_bf16(f1.y); v0[6] = f32_bf16(f1.z); v0[7] = f32_bf16(f1.w);
    v1[0] = f32_bf16(f2.x); v1[1] = f32_bf16(f2.y); v1[2] = f32_bf16(f2.z); v1[3] = f32_bf16(f2.w);
    v1[4] = f32_bf16(f3.x); v1[5] = f32_bf16(f3.y); v1[6] = f32_bf16(f3.z); v1[7] = f32_bf16(f3.w);
    *(us8*)&As[lds_idx(srow, s0)]     = v0;
    *(us8*)&As[lds_idx(srow, s0 + 1)] = v1;
    // stage B (already bf16): 32B per thread
    const unsigned short* gb = WT + (size_t)(n0 + srow) * DIN + k0 + s0 * 8;
    *(us8*)&Bs[lds_idx(srow, s0)]     = *reinterpret_cast<const us8*>(gb);
    *(us8*)&Bs[lds_idx(srow, s0 + 1)] = *reinterpret_cast<const us8*>(gb + 8);
    __syncthreads();

    bf8 af[4], bfr[4];
#pragma unroll
    for (int i = 0; i < 4; ++i)
      af[i] = as_bf8(*(const us8*)&As[lds_idx(wm + i * 16 + l15, lhi)]);
#pragma unroll
    for (int r = 0; r < 4; ++r)
      bfr[r] = as_bf8(*(const us8*)&Bs[lds_idx(wn + r * 16 + l15, lhi)]);
#pragma unroll
    for (int i = 0; i < 4; ++i)
#pragma unroll
      for (int r = 0; r < 4; ++r)
        acc[i][r] = __builtin_amdgcn_mfma_f32_16x16x32_bf16(af[i], bfr[r], acc[i][r], 0, 0, 0);
    __syncthreads();
  }
  // epilogue: C row m -> xp row (m&511)*64 + (m>>9)   ([s][b] layout)
#pragma unroll
  for (int i = 0; i < 4; ++i)
#pragma unroll
    for (int r = 0; r < 4; ++r)
#pragma unroll
      for (int j = 0; j < 4; ++j) {
        int gm = m0 + wm + i * 16 + lhi * 4 + j;
        int gn = n0 + wn + r * 16 + l15;
        int orow = ((gm & 511) << 6) | (gm >> 9);
        XP[(size_t)orow * DH + gn] = f32_bf16(acc[i][r][j]);
      }
}

// ---------------------------------------------------------------- phase 2
// 64 WGs x 256 thr. WG g: batch-group bg=g>>4 (rows bg*16..+16),
// col-group ng=g&15; wave w owns cols ng*64+w*16..+16.
// Per wave: W_hh^T col-slice as 32 bf16x8 frags in VGPRs (loaded once).
// Per step: 32 MFMA (16x16x32) accumulating h@W, + xp + bias, tanh,
// write fp32 out + bf16 h_next; 16-WG batch-group barrier.
__global__ __launch_bounds__(256) void k_rnn(
    const unsigned short* __restrict__ WT,  // W_hh^T bf16 [n][k]
    const unsigned short* __restrict__ XP,  // bf16 [s][b][h]
    const float* __restrict__ BH,           // b_h fp32 [DH]
    float* __restrict__ OUT,                // fp32 [b][s][h]
    unsigned short* __restrict__ H,         // 2 x [NB][DH] bf16
    unsigned int* __restrict__ ctr) {       // 4 counters (zeroed per call)
  const int tid = threadIdx.x, g = blockIdx.x;
  const int w = tid >> 6, lane = tid & 63;
  const int bg = g >> 4, ng = g & 15;
  const int nbase = ng * 64 + w * 16;
  const int rowbase = bg * 16;
  const int l15 = lane & 15, lhi = lane >> 4;
  const int crow = lhi * 4;

  // preload W_hh^T fragments: 32 x 16B per lane = 128 VGPRs
  bf8 bw[32];
  const unsigned short* wp = WT + (size_t)(nbase + l15) * DIN + lhi * 8;
#pragma unroll
  for (int kk = 0; kk < 32; ++kk)
    bw[kk] = as_bf8(*reinterpret_cast<const us8*>(wp + kk * 32));

  const float bh = BH[nbase + l15];

#pragma unroll 1
  for (int t = 0; t < NS; ++t) {
    const int p = t & 1;
    // prefetch xp for this step (independent of h)
    float xpv[4];
#pragma unroll
    for (int j = 0; j < 4; ++j)
      xpv[j] = bf16_f32(XP[(size_t)((t << 6) + rowbase + crow + j) * DH + nbase + l15]);

    f32x4 a0 = {}, a1 = {}, a2 = {}, a3 = {};
    if (t > 0) {
      const unsigned short* hp = H + p * (NB * DH) + (size_t)(rowbase + l15) * DH + lhi * 8;
#pragma unroll
      for (int kk = 0; kk < 32; kk += 4) {
        bf8 h0 = as_bf8(*reinterpret_cast<const us8*>(hp + kk * 32));
        bf8 h1 = as_bf8(*reinterpret_cast<const us8*>(hp + (kk + 1) * 32));
        bf8 h2 = as_bf8(*reinterpret_cast<const us8*>(hp + (kk + 2) * 32));
        bf8 h3 = as_bf8(*reinterpret_cast<const us8*>(hp + (kk + 3) * 32));
        a0 = __builtin_amdgcn_mfma_f32_16x16x32_bf16(h0, bw[kk],     a0, 0, 0, 0);
        a1 = __builtin_amdgcn_mfma_f32_16x16x32_bf16(h1, bw[kk + 1], a1, 0, 0, 0);
        a2 = __builtin_amdgcn_mfma_f32_16x16x32_bf16(h2, bw[kk + 2], a2, 0, 0, 0);
        a3 = __builtin_amdgcn_mfma_f32_16x16x32_bf16(h3, bw[kk + 3], a3, 0, 0, 0);
      }
    }
    f32x4 s01 = a0 + a1, s23 = a2 + a3;
    f32x4 s = s01 + s23;

    unsigned short* hnext = H + (p ^ 1) * (NB * DH);
#pragma unroll
    for (int j = 0; j < 4; ++j) {
      const int gr = rowbase + crow + j;
      float x = xpv[j] + s[j] + bh;
      // tanh via fast exp: tanh(x) = sign(x) * (1-e^{-2|x|})/(1+e^{-2|x|})
      float e = __expf(-2.f * fabsf(x));
      float r = __fdividef(1.f - e, 1.f + e);
      float v = copysignf(r, x);
      OUT[(size_t)(gr * NS + t) * DH + nbase + l15] = v;
      hnext[(size_t)gr * DH + nbase + l15] = f32_bf16(v);
    }

    if (t < NS - 1) {
      __syncthreads();
      if (tid == 0) {
        __hip_atomic_fetch_add(&ctr[bg], 1u, __ATOMIC_RELEASE, __HIP_MEMORY_SCOPE_AGENT);
        const unsigned target = 16u * (unsigned)(t + 1);
        while (__hip_atomic_load(&ctr[bg], __ATOMIC_ACQUIRE, __HIP_MEMORY_SCOPE_AGENT) < target) {
        }
      }
      __syncthreads();
    }
  }
}

// ---------------------------------------------------------------- launcher
extern "C" void kernel_launch(void* const* d_in, const int* in_sizes, int n_in,
                              void* d_out, int out_size, void* d_ws, size_t ws_size,
                              hipStream_t stream) {
  (void)in_sizes; (void)n_in; (void)out_size; (void)ws_size;
  const float* X   = (const float*)d_in[0];  // [64][512][1024]
  const float* Wxh = (const float*)d_in[1];  // [1024][1024]
  const float* Whh = (const float*)d_in[2];  // [1024][1024]
  const float* bh  = (const float*)d_in[3];  // [1024]
  float* out = (float*)d_out;

  char* ws = (char*)d_ws;
  // layout (bytes): wxh_t 2MB | whh_t 2MB | xp 64MB | h 256KB | ctr 64B  (~68.3MB)
  unsigned short* wxh_t = (unsigned short*)(ws);
  unsigned short* whh_t = (unsigned short*)(ws + (size_t)2 * 1024 * 1024);
  unsigned short* xp    = (unsigned short*)(ws + (size_t)4 * 1024 * 1024);
  unsigned short* hbuf  = (unsigned short*)(ws + 71303168ull);
  unsigned int*   ctr   = (unsigned int*)(ws + 71565312ull);

  hipMemsetAsync(ctr, 0, 64, stream);  // barrier counters must start at 0 each call
  k_transpose_bf16<<<1024, 256, 0, stream>>>(Wxh, wxh_t);
  k_transpose_bf16<<<1024, 256, 0, stream>>>(Whh, whh_t);
  k_xproj<<<2048, 256, 0, stream>>>(X, wxh_t, xp);
  k_rnn<<<64, 256, 0, stream>>>(whh_t, xp, bh, out, hbuf, ctr);
}

// Round 3
// 2985.765 us; speedup vs baseline: 1.3105x; 1.3105x over previous
//
#include <hip/hip_runtime.h>
#include <cstdint>

// MyRNN: out[b,t,:] = h_t where h_t = tanh(x[b,t,:]@W_xh + b_h + h_{t-1}@W_hh)
// B=64, S=512, D_IN=D_H=1024, fp32 I/O; internal bf16 MFMA.
//
// Phase 2 sync design: NO acquire/release cache maintenance.
// h exchange via RELAXED agent-scope atomics (sc0 sc1 -> coherent point/L3,
// no buffer_wbl2 / buffer_inv), manual ordering with s_waitcnt vmcnt(0) +
// __syncthreads before a RELAXED counter increment. XP/W stay in cacheable
// loads (L2 never invalidated now). h staged via LDS once per WG (32KB,
// XOR-swizzled for conflict-free ds_read_b128).

#define DIN 1024
#define DH  1024
#define NB  64
#define NS  512

typedef __attribute__((ext_vector_type(8))) unsigned short us8;
typedef __attribute__((ext_vector_type(8))) __bf16 bf8;
typedef __attribute__((ext_vector_type(4))) float f32x4;

__device__ __forceinline__ unsigned short f32_bf16(float f) {
  unsigned u = __float_as_uint(f);
  u = (u + 0x7fffu + ((u >> 16) & 1u)) >> 16;
  return (unsigned short)u;
}
__device__ __forceinline__ float bf16_f32(unsigned short h) {
  return __uint_as_float(((unsigned)h) << 16);
}
__device__ __forceinline__ bf8 as_bf8(us8 v) { return __builtin_bit_cast(bf8, v); }

// ---------------------------------------------------------------- transpose
__global__ __launch_bounds__(256) void k_transpose_bf16(
    const float* __restrict__ W, unsigned short* __restrict__ WT) {
  __shared__ float tile[32][33];
  const int b  = blockIdx.x;
  const int bn = (b & 31) * 32;
  const int bk = (b >> 5) * 32;
  const int tx = threadIdx.x & 31, ty = threadIdx.x >> 5;
#pragma unroll
  for (int i = 0; i < 4; ++i)
    tile[ty + i * 8][tx] = W[(size_t)(bk + ty + i * 8) * DH + bn + tx];
  __syncthreads();
#pragma unroll
  for (int i = 0; i < 4; ++i)
    WT[(size_t)(bn + ty + i * 8) * DIN + bk + tx] = f32_bf16(tile[tx][ty + i * 8]);
}

// ---------------------------------------------------------------- phase 1
__device__ __forceinline__ int lds_idx(int row, int slot) {  // ushort units
  return row * 32 + ((slot ^ ((row >> 1) & 3)) << 3);
}

__global__ __launch_bounds__(256) void k_xproj(
    const float* __restrict__ X,             // [B*S][DIN] fp32
    const unsigned short* __restrict__ WT,   // W_xh^T bf16 [n][k]
    unsigned short* __restrict__ XP) {       // bf16 [s][b][h]
  __shared__ unsigned short As[128 * 32];
  __shared__ unsigned short Bs[128 * 32];
  const int tid = threadIdx.x;
  const int m0 = (int)(blockIdx.x >> 3) * 128;
  const int n0 = (int)(blockIdx.x & 7) * 128;
  const int w = tid >> 6, lane = tid & 63;
  const int wm = (w >> 1) * 64, wn = (w & 1) * 64;
  const int l15 = lane & 15, lhi = lane >> 4;
  const int srow = tid >> 1;
  const int s0 = (tid & 1) * 2;
  f32x4 acc[4][4] = {};

  for (int k0 = 0; k0 < DIN; k0 += 32) {
    const float4* ga = reinterpret_cast<const float4*>(
        X + (size_t)(m0 + srow) * DIN + k0 + s0 * 8);
    float4 f0 = ga[0], f1 = ga[1], f2 = ga[2], f3 = ga[3];
    us8 v0, v1;
    v0[0] = f32_bf16(f0.x); v0[1] = f32_bf16(f0.y); v0[2] = f32_bf16(f0.z); v0[3] = f32_bf16(f0.w);
    v0[4] = f32_bf16(f1.x); v0[5] = f32_bf16(f1.y); v0[6] = f32_bf16(f1.z); v0[7] = f32_bf16(f1.w);
    v1[0] = f32_bf16(f2.x); v1[1] = f32_bf16(f2.y); v1[2] = f32_bf16(f2.z); v1[3] = f32_bf16(f2.w);
    v1[4] = f32_bf16(f3.x); v1[5] = f32_bf16(f3.y); v1[6] = f32_bf16(f3.z); v1[7] = f32_bf16(f3.w);
    *(us8*)&As[lds_idx(srow, s0)]     = v0;
    *(us8*)&As[lds_idx(srow, s0 + 1)] = v1;
    const unsigned short* gb = WT + (size_t)(n0 + srow) * DIN + k0 + s0 * 8;
    *(us8*)&Bs[lds_idx(srow, s0)]     = *reinterpret_cast<const us8*>(gb);
    *(us8*)&Bs[lds_idx(srow, s0 + 1)] = *reinterpret_cast<const us8*>(gb + 8);
    __syncthreads();

    bf8 af[4], bfr[4];
#pragma unroll
    for (int i = 0; i < 4; ++i)
      af[i] = as_bf8(*(const us8*)&As[lds_idx(wm + i * 16 + l15, lhi)]);
#pragma unroll
    for (int r = 0; r < 4; ++r)
      bfr[r] = as_bf8(*(const us8*)&Bs[lds_idx(wn + r * 16 + l15, lhi)]);
#pragma unroll
    for (int i = 0; i < 4; ++i)
#pragma unroll
      for (int r = 0; r < 4; ++r)
        acc[i][r] = __builtin_amdgcn_mfma_f32_16x16x32_bf16(af[i], bfr[r], acc[i][r], 0, 0, 0);
    __syncthreads();
  }
#pragma unroll
  for (int i = 0; i < 4; ++i)
#pragma unroll
    for (int r = 0; r < 4; ++r)
#pragma unroll
      for (int j = 0; j < 4; ++j) {
        int gm = m0 + wm + i * 16 + lhi * 4 + j;
        int gn = n0 + wn + r * 16 + l15;
        int orow = ((gm & 511) << 6) | (gm >> 9);
        XP[(size_t)orow * DH + gn] = f32_bf16(acc[i][r][j]);
      }
}

// ---------------------------------------------------------------- phase 2
// 64 WGs x 256 thr. WG g: batch-group bg=g>>4 (rows bg*16..+16),
// col-group ng=g&15; wave w owns cols ng*64+w*16..+16.
// W_hh^T slice resident in 128 VGPRs/wave. Per step:
//   stage h[p] (16x1024 bf16, 32KB) -> LDS via relaxed-agent 8B loads,
//   32 MFMA, tanh, h stores via relaxed-agent 2B stores,
//   vmcnt(0)+syncthreads, relaxed counter add, OUT stores, poll, syncthreads.
__global__ __launch_bounds__(256) void k_rnn(
    const unsigned short* __restrict__ WT,  // W_hh^T bf16 [n][k]
    const unsigned short* __restrict__ XP,  // bf16 [s][b][h]
    const float* __restrict__ BH,           // b_h fp32
    float* __restrict__ OUT,                // fp32 [b][s][h]
    unsigned short* __restrict__ H,         // 2 x [NB][DH] bf16
    unsigned int* __restrict__ ctr) {       // counters at stride 16 u32 (64B)
  __shared__ us8 hs[16 * 128];              // 16 rows x 128 slot16 = 32KB
  const int tid = threadIdx.x, g = blockIdx.x;
  const int w = tid >> 6, lane = tid & 63;
  const int bg = g >> 4, ng = g & 15;
  const int nbase = ng * 64 + w * 16;
  const int rowbase = bg * 16;
  const int l15 = lane & 15, lhi = lane >> 4;
  const int crow = lhi * 4;
  // staging role: thread covers row srow, 16 x 8B chunks starting at scol
  const int srow = tid >> 4;
  const int scol = (tid & 15) * 16;         // 8B units (256 per row)
  const int sxor = (srow & 7);

  // preload W_hh^T fragments: 32 x 16B per lane = 128 VGPRs
  bf8 bw[32];
  const unsigned short* wp = WT + (size_t)(nbase + l15) * DIN + lhi * 8;
#pragma unroll
  for (int kk = 0; kk < 32; ++kk)
    bw[kk] = as_bf8(*reinterpret_cast<const us8*>(wp + kk * 32));

  const float bh = BH[nbase + l15];
  unsigned long long* lrow = (unsigned long long*)&hs[0] + srow * 256;

#pragma unroll 1
  for (int t = 0; t < NS; ++t) {
    const int p = t & 1;
    // xp for this step (normal cached loads; L2 is never invalidated now)
    float xpv[4];
#pragma unroll
    for (int j = 0; j < 4; ++j)
      xpv[j] = bf16_f32(XP[(size_t)((t << 6) + rowbase + crow + j) * DH + nbase + l15]);

    f32x4 a0 = {}, a1 = {}, a2 = {}, a3 = {};
    if (t > 0) {
      // stage h[p] -> LDS (coherent-point loads, no cache maintenance)
      const unsigned long long* hsrc =
          (const unsigned long long*)(H + (size_t)p * (NB * DH) +
                                      (size_t)(rowbase + srow) * DH) + scol;
      unsigned long long hv[16];
#pragma unroll
      for (int i = 0; i < 16; ++i)
        hv[i] = __hip_atomic_load(hsrc + i, __ATOMIC_RELAXED, __HIP_MEMORY_SCOPE_AGENT);
#pragma unroll
      for (int i = 0; i < 16; ++i) {
        const int c = scol + i;
        const int sp = ((c >> 1) ^ sxor);
        lrow[sp * 2 + (c & 1)] = hv[i];
      }
      __syncthreads();
      const int rx = (l15 & 7);
#pragma unroll
      for (int kk = 0; kk < 32; kk += 4) {
        bf8 h0 = as_bf8(hs[l15 * 128 + ((lhi + (kk    ) * 4) ^ rx)]);
        bf8 h1 = as_bf8(hs[l15 * 128 + ((lhi + (kk + 1) * 4) ^ rx)]);
        bf8 h2 = as_bf8(hs[l15 * 128 + ((lhi + (kk + 2) * 4) ^ rx)]);
        bf8 h3 = as_bf8(hs[l15 * 128 + ((lhi + (kk + 3) * 4) ^ rx)]);
        a0 = __builtin_amdgcn_mfma_f32_16x16x32_bf16(h0, bw[kk],     a0, 0, 0, 0);
        a1 = __builtin_amdgcn_mfma_f32_16x16x32_bf16(h1, bw[kk + 1], a1, 0, 0, 0);
        a2 = __builtin_amdgcn_mfma_f32_16x16x32_bf16(h2, bw[kk + 2], a2, 0, 0, 0);
        a3 = __builtin_amdgcn_mfma_f32_16x16x32_bf16(h3, bw[kk + 3], a3, 0, 0, 0);
      }
    }
    f32x4 s = (a0 + a1) + (a2 + a3);

    unsigned short* hnext = H + (size_t)(p ^ 1) * (NB * DH);
    float v[4];
#pragma unroll
    for (int j = 0; j < 4; ++j) {
      float x = xpv[j] + s[j] + bh;
      float e = __expf(-2.f * fabsf(x));
      float r = __fdividef(1.f - e, 1.f + e);
      v[j] = copysignf(r, x);
    }
    if (t < NS - 1) {
      // h stores to coherent point (relaxed agent scope: sc flags, no wbl2)
#pragma unroll
      for (int j = 0; j < 4; ++j)
        __hip_atomic_store(hnext + (size_t)(rowbase + crow + j) * DH + nbase + l15,
                           f32_bf16(v[j]), __ATOMIC_RELAXED, __HIP_MEMORY_SCOPE_AGENT);
      asm volatile("s_waitcnt vmcnt(0)" ::: "memory");
      __syncthreads();  // all 256 threads' h stores are at the coherent point
      if (tid == 0)
        __hip_atomic_fetch_add(&ctr[bg * 16], 1u, __ATOMIC_RELAXED,
                               __HIP_MEMORY_SCOPE_AGENT);
      // OUT stores off the critical path (normal cached stores)
#pragma unroll
      for (int j = 0; j < 4; ++j)
        OUT[((size_t)(rowbase + crow + j) * NS + t) * DH + nbase + l15] = v[j];
      if (tid == 0) {
        const unsigned target = 16u * (unsigned)(t + 1);
        while (__hip_atomic_load(&ctr[bg * 16], __ATOMIC_RELAXED,
                                 __HIP_MEMORY_SCOPE_AGENT) < target) {
        }
      }
      __syncthreads();
      asm volatile("" ::: "memory");  // no staging-load hoist above the poll
    } else {
#pragma unroll
      for (int j = 0; j < 4; ++j)
        OUT[((size_t)(rowbase + crow + j) * NS + t) * DH + nbase + l15] = v[j];
    }
  }
}

// ---------------------------------------------------------------- launcher
extern "C" void kernel_launch(void* const* d_in, const int* in_sizes, int n_in,
                              void* d_out, int out_size, void* d_ws, size_t ws_size,
                              hipStream_t stream) {
  (void)in_sizes; (void)n_in; (void)out_size; (void)ws_size;
  const float* X   = (const float*)d_in[0];
  const float* Wxh = (const float*)d_in[1];
  const float* Whh = (const float*)d_in[2];
  const float* bh  = (const float*)d_in[3];
  float* out = (float*)d_out;

  char* ws = (char*)d_ws;
  // layout: wxh_t 2MB | whh_t 2MB | xp 64MB | h 256KB | ctr 256B
  unsigned short* wxh_t = (unsigned short*)(ws);
  unsigned short* whh_t = (unsigned short*)(ws + (size_t)2 * 1024 * 1024);
  unsigned short* xp    = (unsigned short*)(ws + (size_t)4 * 1024 * 1024);
  unsigned short* hbuf  = (unsigned short*)(ws + 71303168ull);
  unsigned int*   ctr   = (unsigned int*)(ws + 71565312ull);

  (void)hipMemsetAsync(ctr, 0, 256, stream);  // counters start at 0 each call
  k_transpose_bf16<<<1024, 256, 0, stream>>>(Wxh, wxh_t);
  k_transpose_bf16<<<1024, 256, 0, stream>>>(Whh, whh_t);
  k_xproj<<<2048, 256, 0, stream>>>(X, wxh_t, xp);
  k_rnn<<<64, 256, 0, stream>>>(whh_t, xp, bh, out, hbuf, ctr);
}

// Round 4
// 1837.434 us; speedup vs baseline: 2.1294x; 1.6250x over previous
//
#include <hip/hip_runtime.h>
#include <cstdint>

// MyRNN: out[b,t,:] = h_t where h_t = tanh(x[b,t,:]@W_xh + b_h + h_{t-1}@W_hh)
// B=64, S=512, D_IN=D_H=1024, fp32 I/O; internal bf16 MFMA.
//
// Round 4: (1) conflict-free LDS staging swizzle (linear 16B chunks,
// slot = r*128 + (c8 ^ (r&7)) — conflict-free on BOTH write and read),
// (2) per-wave arrivals + double-buffered h LDS -> ONE __syncthreads/step,
// (3) xp[t+1] prefetched under the poll, nontemporal OUT stores,
// (4) 16B sc0sc1 staging loads via inline asm (cache-bypass, not atomic).

#define DIN 1024
#define DH  1024
#define NB  64
#define NS  512

typedef __attribute__((ext_vector_type(8))) unsigned short us8;
typedef __attribute__((ext_vector_type(8))) __bf16 bf8;
typedef __attribute__((ext_vector_type(4))) float f32x4;

__device__ __forceinline__ unsigned short f32_bf16(float f) {
  unsigned u = __float_as_uint(f);
  u = (u + 0x7fffu + ((u >> 16) & 1u)) >> 16;
  return (unsigned short)u;
}
__device__ __forceinline__ float bf16_f32(unsigned short h) {
  return __uint_as_float(((unsigned)h) << 16);
}
__device__ __forceinline__ bf8 as_bf8(us8 v) { return __builtin_bit_cast(bf8, v); }

// 16B load with coherent-point bypass (sc0 sc1): data races are on distinct
// 2B elements; we only need the cache-bypass semantics, not atomicity.
__device__ __forceinline__ us8 load_sc16(const us8* p) {
  us8 r;
  asm volatile("global_load_dwordx4 %0, %1, off sc0 sc1"
               : "=v"(r) : "v"(p) : "memory");
  return r;
}

// ---------------------------------------------------------------- transpose
__global__ __launch_bounds__(256) void k_transpose_bf16(
    const float* __restrict__ W, unsigned short* __restrict__ WT) {
  __shared__ float tile[32][33];
  const int b  = blockIdx.x;
  const int bn = (b & 31) * 32;
  const int bk = (b >> 5) * 32;
  const int tx = threadIdx.x & 31, ty = threadIdx.x >> 5;
#pragma unroll
  for (int i = 0; i < 4; ++i)
    tile[ty + i * 8][tx] = W[(size_t)(bk + ty + i * 8) * DH + bn + tx];
  __syncthreads();
#pragma unroll
  for (int i = 0; i < 4; ++i)
    WT[(size_t)(bn + ty + i * 8) * DIN + bk + tx] = f32_bf16(tile[tx][ty + i * 8]);
}

// ---------------------------------------------------------------- phase 1
__device__ __forceinline__ int lds_idx(int row, int slot) {  // ushort units
  return row * 32 + ((slot ^ ((row >> 1) & 3)) << 3);
}

__global__ __launch_bounds__(256) void k_xproj(
    const float* __restrict__ X,             // [B*S][DIN] fp32
    const unsigned short* __restrict__ WT,   // W_xh^T bf16 [n][k]
    unsigned short* __restrict__ XP) {       // bf16 [s][b][h]
  __shared__ unsigned short As[128 * 32];
  __shared__ unsigned short Bs[128 * 32];
  const int tid = threadIdx.x;
  const int m0 = (int)(blockIdx.x >> 3) * 128;
  const int n0 = (int)(blockIdx.x & 7) * 128;
  const int w = tid >> 6, lane = tid & 63;
  const int wm = (w >> 1) * 64, wn = (w & 1) * 64;
  const int l15 = lane & 15, lhi = lane >> 4;
  const int srow = tid >> 1;
  const int s0 = (tid & 1) * 2;
  f32x4 acc[4][4] = {};

  for (int k0 = 0; k0 < DIN; k0 += 32) {
    const float4* ga = reinterpret_cast<const float4*>(
        X + (size_t)(m0 + srow) * DIN + k0 + s0 * 8);
    float4 f0 = ga[0], f1 = ga[1], f2 = ga[2], f3 = ga[3];
    us8 v0, v1;
    v0[0] = f32_bf16(f0.x); v0[1] = f32_bf16(f0.y); v0[2] = f32_bf16(f0.z); v0[3] = f32_bf16(f0.w);
    v0[4] = f32_bf16(f1.x); v0[5] = f32_bf16(f1.y); v0[6] = f32_bf16(f1.z); v0[7] = f32_bf16(f1.w);
    v1[0] = f32_bf16(f2.x); v1[1] = f32_bf16(f2.y); v1[2] = f32_bf16(f2.z); v1[3] = f32_bf16(f2.w);
    v1[4] = f32_bf16(f3.x); v1[5] = f32_bf16(f3.y); v1[6] = f32_bf16(f3.z); v1[7] = f32_bf16(f3.w);
    *(us8*)&As[lds_idx(srow, s0)]     = v0;
    *(us8*)&As[lds_idx(srow, s0 + 1)] = v1;
    const unsigned short* gb = WT + (size_t)(n0 + srow) * DIN + k0 + s0 * 8;
    *(us8*)&Bs[lds_idx(srow, s0)]     = *reinterpret_cast<const us8*>(gb);
    *(us8*)&Bs[lds_idx(srow, s0 + 1)] = *reinterpret_cast<const us8*>(gb + 8);
    __syncthreads();

    bf8 af[4], bfr[4];
#pragma unroll
    for (int i = 0; i < 4; ++i)
      af[i] = as_bf8(*(const us8*)&As[lds_idx(wm + i * 16 + l15, lhi)]);
#pragma unroll
    for (int r = 0; r < 4; ++r)
      bfr[r] = as_bf8(*(const us8*)&Bs[lds_idx(wn + r * 16 + l15, lhi)]);
#pragma unroll
    for (int i = 0; i < 4; ++i)
#pragma unroll
      for (int r = 0; r < 4; ++r)
        acc[i][r] = __builtin_amdgcn_mfma_f32_16x16x32_bf16(af[i], bfr[r], acc[i][r], 0, 0, 0);
    __syncthreads();
  }
#pragma unroll
  for (int i = 0; i < 4; ++i)
#pragma unroll
    for (int r = 0; r < 4; ++r)
#pragma unroll
      for (int j = 0; j < 4; ++j) {
        int gm = m0 + wm + i * 16 + lhi * 4 + j;
        int gn = n0 + wn + r * 16 + l15;
        int orow = ((gm & 511) << 6) | (gm >> 9);
        XP[(size_t)orow * DH + gn] = f32_bf16(acc[i][r][j]);
      }
}

// ---------------------------------------------------------------- phase 2
// 64 WGs x 256 thr. WG g: bg=g>>4 (rows bg*16..+16), ng=g&15; wave w owns
// cols ng*64+w*16..+16. W_hh^T slice resident in 128 VGPRs/wave.
// LDS h tile: 2 buffers x 2048 16B-chunks; chunk gc=(r<<7)|c8 of the global
// [16][1024] bf16 tile stored at slot r*128 + (c8 ^ (r&7)) -> conflict-free
// writes (lane-linear gc) AND conflict-free A-fragment reads.
__global__ __launch_bounds__(256) void k_rnn(
    const unsigned short* __restrict__ WT,  // W_hh^T bf16 [n][k]
    const unsigned short* __restrict__ XP,  // bf16 [s][b][h]
    const float* __restrict__ BH,           // b_h fp32
    float* __restrict__ OUT,                // fp32 [b][s][h]
    unsigned short* __restrict__ H,         // 2 x [NB][DH] bf16
    unsigned int* __restrict__ ctr) {       // counters at stride 16 u32
  __shared__ us8 hs[2][2048];               // 2 x 32KB
  const int tid = threadIdx.x, g = blockIdx.x;
  const int w = tid >> 6, lane = tid & 63;
  const int bg = g >> 4, ng = g & 15;
  const int nbase = ng * 64 + w * 16;
  const int rowbase = bg * 16;
  const int l15 = lane & 15, lhi = lane >> 4;
  const int crow = lhi * 4;
  const int th = tid >> 7;                  // staging row parity
  const int c7 = tid & 127;                 // staging chunk-in-row
  const int rbase = l15 * 128;              // read: row base (16B slots)
  const int rx = l15 & 7;                   // read: XOR key

  // preload W_hh^T fragments: 32 x 16B per lane = 128 VGPRs
  bf8 bw[32];
  const unsigned short* wp = WT + (size_t)(nbase + l15) * DIN + lhi * 8;
#pragma unroll
  for (int kk = 0; kk < 32; ++kk)
    bw[kk] = as_bf8(*reinterpret_cast<const us8*>(wp + kk * 32));

  const float bh = BH[nbase + l15];
  unsigned int* myctr = &ctr[bg * 16];

  // prefetch xp for t=0
  float xq[4];
#pragma unroll
  for (int j = 0; j < 4; ++j)
    xq[j] = bf16_f32(XP[(size_t)(rowbase + crow + j) * DH + nbase + l15]);

#pragma unroll 1
  for (int t = 0; t < NS; ++t) {
    const int pb = t & 1;
    f32x4 a0 = {}, a1 = {}, a2 = {}, a3 = {};
    if (t > 0) {
      // ---- stage h[pb] -> hs[pb] (16B sc-bypass loads, lane-linear) ----
      const us8* hg = reinterpret_cast<const us8*>(H) +
                      (size_t)pb * 8192 + rowbase * 128 + tid;
      us8 hv[8];
#pragma unroll
      for (int i = 0; i < 8; ++i) hv[i] = load_sc16(hg + 256 * i);
      asm volatile("s_waitcnt vmcnt(0)" ::: "memory");
#pragma unroll
      for (int i = 0; i < 8; ++i) {
        const int r = 2 * i + th;
        hs[pb][r * 128 + (c7 ^ (r & 7))] = hv[i];
      }
      __syncthreads();  // the ONLY barrier per step
      // ---- A-fragment reads + 32 MFMA ----
#pragma unroll
      for (int kk = 0; kk < 32; kk += 4) {
        bf8 h0 = as_bf8(hs[pb][rbase + (((kk + 0) * 4 + lhi) ^ rx)]);
        bf8 h1 = as_bf8(hs[pb][rbase + (((kk + 1) * 4 + lhi) ^ rx)]);
        bf8 h2 = as_bf8(hs[pb][rbase + (((kk + 2) * 4 + lhi) ^ rx)]);
        bf8 h3 = as_bf8(hs[pb][rbase + (((kk + 3) * 4 + lhi) ^ rx)]);
        a0 = __builtin_amdgcn_mfma_f32_16x16x32_bf16(h0, bw[kk],     a0, 0, 0, 0);
        a1 = __builtin_amdgcn_mfma_f32_16x16x32_bf16(h1, bw[kk + 1], a1, 0, 0, 0);
        a2 = __builtin_amdgcn_mfma_f32_16x16x32_bf16(h2, bw[kk + 2], a2, 0, 0, 0);
        a3 = __builtin_amdgcn_mfma_f32_16x16x32_bf16(h3, bw[kk + 3], a3, 0, 0, 0);
      }
    }
    f32x4 s = (a0 + a1) + (a2 + a3);

    float v[4];
#pragma unroll
    for (int j = 0; j < 4; ++j) {
      float x = xq[j] + s[j] + bh;
      float e = __expf(-2.f * fabsf(x));
      float r = __fdividef(1.f - e, 1.f + e);
      v[j] = copysignf(r, x);
    }

    if (t < NS - 1) {
      // h stores to coherent point
      unsigned short* hnext = H + (size_t)(pb ^ 1) * (NB * DH);
#pragma unroll
      for (int j = 0; j < 4; ++j)
        __hip_atomic_store(hnext + (size_t)(rowbase + crow + j) * DH + nbase + l15,
                           f32_bf16(v[j]), __ATOMIC_RELAXED, __HIP_MEMORY_SCOPE_AGENT);
      asm volatile("s_waitcnt vmcnt(0)" ::: "memory");  // drain THIS wave's h
      if (lane == 0)  // per-WAVE arrival: 64 arrivals per step per bg
        __hip_atomic_fetch_add(myctr, 1u, __ATOMIC_RELAXED, __HIP_MEMORY_SCOPE_AGENT);
      // off-critical-path work under the poll:
#pragma unroll
      for (int j = 0; j < 4; ++j)
        __builtin_nontemporal_store(
            v[j], &OUT[((size_t)(rowbase + crow + j) * NS + t) * DH + nbase + l15]);
#pragma unroll
      for (int j = 0; j < 4; ++j)
        xq[j] = bf16_f32(XP[(size_t)(((t + 1) << 6) + rowbase + crow + j) * DH +
                            nbase + l15]);
      const unsigned target = 64u * (unsigned)(t + 1);
      while (__hip_atomic_load(myctr, __ATOMIC_RELAXED, __HIP_MEMORY_SCOPE_AGENT) <
             target) {
      }
    } else {
#pragma unroll
      for (int j = 0; j < 4; ++j)
        __builtin_nontemporal_store(
            v[j], &OUT[((size_t)(rowbase + crow + j) * NS + t) * DH + nbase + l15]);
    }
  }
}

// ---------------------------------------------------------------- launcher
extern "C" void kernel_launch(void* const* d_in, const int* in_sizes, int n_in,
                              void* d_out, int out_size, void* d_ws, size_t ws_size,
                              hipStream_t stream) {
  (void)in_sizes; (void)n_in; (void)out_size; (void)ws_size;
  const float* X   = (const float*)d_in[0];
  const float* Wxh = (const float*)d_in[1];
  const float* Whh = (const float*)d_in[2];
  const float* bh  = (const float*)d_in[3];
  float* out = (float*)d_out;

  char* ws = (char*)d_ws;
  // layout: wxh_t 2MB | whh_t 2MB | xp 64MB | h 256KB | ctr 256B
  unsigned short* wxh_t = (unsigned short*)(ws);
  unsigned short* whh_t = (unsigned short*)(ws + (size_t)2 * 1024 * 1024);
  unsigned short* xp    = (unsigned short*)(ws + (size_t)4 * 1024 * 1024);
  unsigned short* hbuf  = (unsigned short*)(ws + 71303168ull);
  unsigned int*   ctr   = (unsigned int*)(ws + 71565312ull);

  (void)hipMemsetAsync(ctr, 0, 256, stream);  // counters start at 0 each call
  k_transpose_bf16<<<1024, 256, 0, stream>>>(Wxh, wxh_t);
  k_transpose_bf16<<<1024, 256, 0, stream>>>(Whh, whh_t);
  k_xproj<<<2048, 256, 0, stream>>>(X, wxh_t, xp);
  k_rnn<<<64, 256, 0, stream>>>(whh_t, xp, bh, out, hbuf, ctr);
}

// Round 5
// 1601.483 us; speedup vs baseline: 2.4432x; 1.1473x over previous
//
#include <hip/hip_runtime.h>
#include <cstdint>

// MyRNN: out[b,t,:] = h_t where h_t = tanh(x[b,t,:]@W_xh + b_h + h_{t-1}@W_hh)
// B=64, S=512, D_IN=D_H=1024, fp32 I/O; internal bf16 MFMA.
//
// Round 5 (sync-path tuning):
//  - 4 arrival counter lines per batch-group (one per wave index, 256B apart):
//    16 parallel RMWs/line instead of 64 serialized on one line.
//  - OUT stores moved AFTER the poll (issued with next step's staging loads,
//    acks overlap staging latency) -> poll iterations wait only on poll loads.
//  - s_sleep(1) backoff in the poll loop (less MALL contention on ctr lines).

#define DIN 1024
#define DH  1024
#define NB  64
#define NS  512

typedef __attribute__((ext_vector_type(8))) unsigned short us8;
typedef __attribute__((ext_vector_type(8))) __bf16 bf8;
typedef __attribute__((ext_vector_type(4))) float f32x4;

__device__ __forceinline__ unsigned short f32_bf16(float f) {
  unsigned u = __float_as_uint(f);
  u = (u + 0x7fffu + ((u >> 16) & 1u)) >> 16;
  return (unsigned short)u;
}
__device__ __forceinline__ float bf16_f32(unsigned short h) {
  return __uint_as_float(((unsigned)h) << 16);
}
__device__ __forceinline__ bf8 as_bf8(us8 v) { return __builtin_bit_cast(bf8, v); }

// 16B load with coherent-point bypass (sc0 sc1). NOTE: raw asm loads are not
// tracked by the compiler's waitcnt insertion — callers MUST s_waitcnt vmcnt
// before using the result.
__device__ __forceinline__ us8 load_sc16(const us8* p) {
  us8 r;
  asm volatile("global_load_dwordx4 %0, %1, off sc0 sc1"
               : "=v"(r) : "v"(p) : "memory");
  return r;
}

// ---------------------------------------------------------------- transpose
__global__ __launch_bounds__(256) void k_transpose_bf16(
    const float* __restrict__ W, unsigned short* __restrict__ WT) {
  __shared__ float tile[32][33];
  const int b  = blockIdx.x;
  const int bn = (b & 31) * 32;
  const int bk = (b >> 5) * 32;
  const int tx = threadIdx.x & 31, ty = threadIdx.x >> 5;
#pragma unroll
  for (int i = 0; i < 4; ++i)
    tile[ty + i * 8][tx] = W[(size_t)(bk + ty + i * 8) * DH + bn + tx];
  __syncthreads();
#pragma unroll
  for (int i = 0; i < 4; ++i)
    WT[(size_t)(bn + ty + i * 8) * DIN + bk + tx] = f32_bf16(tile[tx][ty + i * 8]);
}

// ---------------------------------------------------------------- phase 1
__device__ __forceinline__ int lds_idx(int row, int slot) {  // ushort units
  return row * 32 + ((slot ^ ((row >> 1) & 3)) << 3);
}

__global__ __launch_bounds__(256) void k_xproj(
    const float* __restrict__ X,             // [B*S][DIN] fp32
    const unsigned short* __restrict__ WT,   // W_xh^T bf16 [n][k]
    unsigned short* __restrict__ XP) {       // bf16 [s][b][h]
  __shared__ unsigned short As[128 * 32];
  __shared__ unsigned short Bs[128 * 32];
  const int tid = threadIdx.x;
  const int m0 = (int)(blockIdx.x >> 3) * 128;
  const int n0 = (int)(blockIdx.x & 7) * 128;
  const int w = tid >> 6, lane = tid & 63;
  const int wm = (w >> 1) * 64, wn = (w & 1) * 64;
  const int l15 = lane & 15, lhi = lane >> 4;
  const int srow = tid >> 1;
  const int s0 = (tid & 1) * 2;
  f32x4 acc[4][4] = {};

  for (int k0 = 0; k0 < DIN; k0 += 32) {
    const float4* ga = reinterpret_cast<const float4*>(
        X + (size_t)(m0 + srow) * DIN + k0 + s0 * 8);
    float4 f0 = ga[0], f1 = ga[1], f2 = ga[2], f3 = ga[3];
    us8 v0, v1;
    v0[0] = f32_bf16(f0.x); v0[1] = f32_bf16(f0.y); v0[2] = f32_bf16(f0.z); v0[3] = f32_bf16(f0.w);
    v0[4] = f32_bf16(f1.x); v0[5] = f32_bf16(f1.y); v0[6] = f32_bf16(f1.z); v0[7] = f32_bf16(f1.w);
    v1[0] = f32_bf16(f2.x); v1[1] = f32_bf16(f2.y); v1[2] = f32_bf16(f2.z); v1[3] = f32_bf16(f2.w);
    v1[4] = f32_bf16(f3.x); v1[5] = f32_bf16(f3.y); v1[6] = f32_bf16(f3.z); v1[7] = f32_bf16(f3.w);
    *(us8*)&As[lds_idx(srow, s0)]     = v0;
    *(us8*)&As[lds_idx(srow, s0 + 1)] = v1;
    const unsigned short* gb = WT + (size_t)(n0 + srow) * DIN + k0 + s0 * 8;
    *(us8*)&Bs[lds_idx(srow, s0)]     = *reinterpret_cast<const us8*>(gb);
    *(us8*)&Bs[lds_idx(srow, s0 + 1)] = *reinterpret_cast<const us8*>(gb + 8);
    __syncthreads();

    bf8 af[4], bfr[4];
#pragma unroll
    for (int i = 0; i < 4; ++i)
      af[i] = as_bf8(*(const us8*)&As[lds_idx(wm + i * 16 + l15, lhi)]);
#pragma unroll
    for (int r = 0; r < 4; ++r)
      bfr[r] = as_bf8(*(const us8*)&Bs[lds_idx(wn + r * 16 + l15, lhi)]);
#pragma unroll
    for (int i = 0; i < 4; ++i)
#pragma unroll
      for (int r = 0; r < 4; ++r)
        acc[i][r] = __builtin_amdgcn_mfma_f32_16x16x32_bf16(af[i], bfr[r], acc[i][r], 0, 0, 0);
    __syncthreads();
  }
#pragma unroll
  for (int i = 0; i < 4; ++i)
#pragma unroll
    for (int r = 0; r < 4; ++r)
#pragma unroll
      for (int j = 0; j < 4; ++j) {
        int gm = m0 + wm + i * 16 + lhi * 4 + j;
        int gn = n0 + wn + r * 16 + l15;
        int orow = ((gm & 511) << 6) | (gm >> 9);
        XP[(size_t)orow * DH + gn] = f32_bf16(acc[i][r][j]);
      }
}

// ---------------------------------------------------------------- phase 2
// 64 WGs x 256 thr. WG g: bg=g>>4 (rows bg*16..+16), ng=g&15; wave w owns
// cols ng*64+w*16..+16. W_hh^T slice resident in 128 VGPRs/wave.
// Arrival: wave w adds to ctr[(bg*4+w)*64] after draining its h stores;
// line (bg,w) == 16*(t+1) means all wave-w producers of bg finished step t.
// Poll waits on all 4 lines (s_sleep backoff).
__global__ __launch_bounds__(256) void k_rnn(
    const unsigned short* __restrict__ WT,  // W_hh^T bf16 [n][k]
    const unsigned short* __restrict__ XP,  // bf16 [s][b][h]
    const float* __restrict__ BH,           // b_h fp32
    float* __restrict__ OUT,                // fp32 [b][s][h]
    unsigned short* __restrict__ H,         // 2 x [NB][DH] bf16
    unsigned int* __restrict__ ctr) {       // 4 bg x 4 wave lines, 256B apart
  __shared__ us8 hs[2][2048];               // 2 x 32KB
  const int tid = threadIdx.x, g = blockIdx.x;
  const int w = tid >> 6, lane = tid & 63;
  const int bg = g >> 4, ng = g & 15;
  const int nbase = ng * 64 + w * 16;
  const int rowbase = bg * 16;
  const int l15 = lane & 15, lhi = lane >> 4;
  const int crow = lhi * 4;
  const int th = tid >> 7;                  // staging row parity
  const int c7 = tid & 127;                 // staging chunk-in-row
  const int rbase = l15 * 128;              // read: row base (16B slots)
  const int rx = l15 & 7;                   // read: XOR key

  // preload W_hh^T fragments: 32 x 16B per lane = 128 VGPRs
  bf8 bw[32];
  const unsigned short* wp = WT + (size_t)(nbase + l15) * DIN + lhi * 8;
#pragma unroll
  for (int kk = 0; kk < 32; ++kk)
    bw[kk] = as_bf8(*reinterpret_cast<const us8*>(wp + kk * 32));

  const float bh = BH[nbase + l15];
  unsigned int* arr = &ctr[(bg * 4 + w) * 64];   // this wave's arrival line
  unsigned int* p0 = &ctr[(bg * 4 + 0) * 64];
  unsigned int* p1 = &ctr[(bg * 4 + 1) * 64];
  unsigned int* p2 = &ctr[(bg * 4 + 2) * 64];
  unsigned int* p3 = &ctr[(bg * 4 + 3) * 64];

  // prefetch xp for t=0
  float xq[4];
#pragma unroll
  for (int j = 0; j < 4; ++j)
    xq[j] = bf16_f32(XP[(size_t)(rowbase + crow + j) * DH + nbase + l15]);

  float v[4] = {0.f, 0.f, 0.f, 0.f};

#pragma unroll 1
  for (int t = 0; t < NS; ++t) {
    const int pb = t & 1;
    f32x4 a0 = {}, a1 = {}, a2 = {}, a3 = {};
    if (t > 0) {
      // ---- stage h[pb] -> hs[pb]; OUT stores for t-1 overlap the latency ----
      const us8* hg = reinterpret_cast<const us8*>(H) +
                      (size_t)pb * 8192 + rowbase * 128 + tid;
      us8 hv[8];
#pragma unroll
      for (int i = 0; i < 8; ++i) hv[i] = load_sc16(hg + 256 * i);
#pragma unroll
      for (int j = 0; j < 4; ++j)
        __builtin_nontemporal_store(
            v[j],
            &OUT[((size_t)(rowbase + crow + j) * NS + (t - 1)) * DH + nbase + l15]);
      asm volatile("s_waitcnt vmcnt(0)" ::: "memory");
#pragma unroll
      for (int i = 0; i < 8; ++i) {
        const int r = 2 * i + th;
        hs[pb][r * 128 + (c7 ^ (r & 7))] = hv[i];
      }
      __syncthreads();  // the ONLY barrier per step
      // ---- A-fragment reads + 32 MFMA ----
#pragma unroll
      for (int kk = 0; kk < 32; kk += 4) {
        bf8 h0 = as_bf8(hs[pb][rbase + (((kk + 0) * 4 + lhi) ^ rx)]);
        bf8 h1 = as_bf8(hs[pb][rbase + (((kk + 1) * 4 + lhi) ^ rx)]);
        bf8 h2 = as_bf8(hs[pb][rbase + (((kk + 2) * 4 + lhi) ^ rx)]);
        bf8 h3 = as_bf8(hs[pb][rbase + (((kk + 3) * 4 + lhi) ^ rx)]);
        a0 = __builtin_amdgcn_mfma_f32_16x16x32_bf16(h0, bw[kk],     a0, 0, 0, 0);
        a1 = __builtin_amdgcn_mfma_f32_16x16x32_bf16(h1, bw[kk + 1], a1, 0, 0, 0);
        a2 = __builtin_amdgcn_mfma_f32_16x16x32_bf16(h2, bw[kk + 2], a2, 0, 0, 0);
        a3 = __builtin_amdgcn_mfma_f32_16x16x32_bf16(h3, bw[kk + 3], a3, 0, 0, 0);
      }
    }
    f32x4 s = (a0 + a1) + (a2 + a3);

#pragma unroll
    for (int j = 0; j < 4; ++j) {
      float x = xq[j] + s[j] + bh;
      float e = __expf(-2.f * fabsf(x));
      float r = __fdividef(1.f - e, 1.f + e);
      v[j] = copysignf(r, x);
    }

    if (t < NS - 1) {
      // h stores to coherent point
      unsigned short* hnext = H + (size_t)(pb ^ 1) * (NB * DH);
#pragma unroll
      for (int j = 0; j < 4; ++j)
        __hip_atomic_store(hnext + (size_t)(rowbase + crow + j) * DH + nbase + l15,
                           f32_bf16(v[j]), __ATOMIC_RELAXED, __HIP_MEMORY_SCOPE_AGENT);
      asm volatile("s_waitcnt vmcnt(0)" ::: "memory");  // drain THIS wave's h
      if (lane == 0)  // per-wave arrival on this wave's own line
        __hip_atomic_fetch_add(arr, 1u, __ATOMIC_RELAXED, __HIP_MEMORY_SCOPE_AGENT);
      // xp prefetch rides under the poll
#pragma unroll
      for (int j = 0; j < 4; ++j)
        xq[j] = bf16_f32(XP[(size_t)(((t + 1) << 6) + rowbase + crow + j) * DH +
                            nbase + l15]);
      const unsigned tgt = 16u * (unsigned)(t + 1);
      for (;;) {
        unsigned u0 = __hip_atomic_load(p0, __ATOMIC_RELAXED, __HIP_MEMORY_SCOPE_AGENT);
        unsigned u1 = __hip_atomic_load(p1, __ATOMIC_RELAXED, __HIP_MEMORY_SCOPE_AGENT);
        unsigned u2 = __hip_atomic_load(p2, __ATOMIC_RELAXED, __HIP_MEMORY_SCOPE_AGENT);
        unsigned u3 = __hip_atomic_load(p3, __ATOMIC_RELAXED, __HIP_MEMORY_SCOPE_AGENT);
        if ((u0 >= tgt) & (u1 >= tgt) & (u2 >= tgt) & (u3 >= tgt)) break;
        __builtin_amdgcn_s_sleep(1);
      }
      asm volatile("" ::: "memory");  // no staging-load hoist above the poll
    }
  }
  // final OUT stores for t = NS-1
#pragma unroll
  for (int j = 0; j < 4; ++j)
    __builtin_nontemporal_store(
        v[j], &OUT[((size_t)(rowbase + crow + j) * NS + (NS - 1)) * DH + nbase + l15]);
}

// ---------------------------------------------------------------- launcher
extern "C" void kernel_launch(void* const* d_in, const int* in_sizes, int n_in,
                              void* d_out, int out_size, void* d_ws, size_t ws_size,
                              hipStream_t stream) {
  (void)in_sizes; (void)n_in; (void)out_size; (void)ws_size;
  const float* X   = (const float*)d_in[0];
  const float* Wxh = (const float*)d_in[1];
  const float* Whh = (const float*)d_in[2];
  const float* bh  = (const float*)d_in[3];
  float* out = (float*)d_out;

  char* ws = (char*)d_ws;
  // layout: wxh_t 2MB | whh_t 2MB | xp 64MB | h 256KB | ctr 4KB
  unsigned short* wxh_t = (unsigned short*)(ws);
  unsigned short* whh_t = (unsigned short*)(ws + (size_t)2 * 1024 * 1024);
  unsigned short* xp    = (unsigned short*)(ws + (size_t)4 * 1024 * 1024);
  unsigned short* hbuf  = (unsigned short*)(ws + 71303168ull);
  unsigned int*   ctr   = (unsigned int*)(ws + 71565312ull);

  (void)hipMemsetAsync(ctr, 0, 4096, stream);  // counters start at 0 each call
  k_transpose_bf16<<<1024, 256, 0, stream>>>(Wxh, wxh_t);
  k_transpose_bf16<<<1024, 256, 0, stream>>>(Whh, whh_t);
  k_xproj<<<2048, 256, 0, stream>>>(X, wxh_t, xp);
  k_rnn<<<64, 256, 0, stream>>>(whh_t, xp, bh, out, hbuf, ctr);
}